// Round 7
// baseline (245.285 us; speedup 1.0000x reference)
//
#include <hip/hip_runtime.h>
#include <stdint.h>
#include <stddef.h>

typedef __attribute__((ext_vector_type(8))) short bf16x8;
typedef __attribute__((ext_vector_type(4))) float f32x4;
typedef __attribute__((ext_vector_type(4))) int i32x4;

#define NH 128
#define NW 128
#define NC 64
#define NF 256

__device__ __forceinline__ unsigned short f2b(float f) {
  union { float f; uint32_t u; } t; t.f = f;
  uint32_t u = t.u;
  return (unsigned short)((u + 0x7fffu + ((u >> 16) & 1u)) >> 16);
}

// prep: weights in per-wave fragment order, FULL N (16 col-frags):
//   u16 elem (s*32 + cf*2 + kk)*512 + lane*8 + e
//     = kern[(s*64 + (kk*4+(lane>>4))*8 + e)*NF + cf*16 + (lane&15)]
__global__ void prep_bt(const float* __restrict__ kr, unsigned short* __restrict__ bt) {
  int t = blockIdx.x * 256 + threadIdx.x;   // [0, 18432)
  int lane = t & 63;
  int kk   = (t >> 6) & 1;
  int cf   = (t >> 7) & 15;
  int s    = t >> 11;                       // 0..8
  int l15 = lane & 15, l4 = lane >> 4;
  int col = cf * 16 + l15;
  int k0  = s * 64 + (kk * 4 + l4) * 8;
  unsigned short* dst = bt + (size_t)t * 8;
  const float* src = kr + (size_t)k0 * NF + col;
  #pragma unroll
  for (int e = 0; e < 8; ++e) dst[e] = f2b(src[(size_t)e * NF]);
}

#define SLOT 16384   // one x-row bf16: [w=128][cb=8 x 16B], XOR-swizzled

// Strip block: 4 consecutive h rows x FULL N=256. 512 thr = 8 waves (2 wm x 4 wn).
// Rolling 4-slot LDS; one new x-row per step; ONE barrier per step.
// B: register TRIPLE buffer, prefetched 2 shifts ahead: at shift s issue
// B((s+2)%9) -> breg[(s+2)%3]. 9 % 3 == 0 makes the schedule uniform across
// step boundaries (this fixes R6's parity bug: s=0 of every step gets B(0)).
__global__ __launch_bounds__(512, 2)
void conv_main(const float* __restrict__ x, const unsigned short* __restrict__ bt,
               const float* __restrict__ bias, float* __restrict__ out)
{
  __shared__ __align__(16) char lds[4 * SLOT];   // 64 KB

  const int tid  = threadIdx.x;
  const int lane = tid & 63;
  const int l15  = lane & 15;
  const int l4   = lane >> 4;
  const int wid  = tid >> 6;
  const int wm   = wid >> 2;    // 2: w-half
  const int wn   = wid & 3;     // 4: F-quarter

  // XCD-aware bijective swizzle: 512 blocks, 64 per XCD.
  int bid  = (int)blockIdx.x;
  int work = (bid & 7) * 64 + (bid >> 3);
  int strip = work & 31;
  int bb    = work >> 5;
  int h0 = strip * 4;

  const char* btb = (const char*)bt;
  const int bofs = wn * 8192 + lane * 16;   // + s*32768 + n*2048 + kk*1024

  // A-frag LUT: alut[dwi][m]; kk=1 address = kk=0 address XOR 64
  int alut[3][4];
  #pragma unroll
  for (int dwi = 0; dwi < 3; ++dwi)
    #pragma unroll
    for (int m = 0; m < 4; ++m) {
      int ws = (wm * 64 + m * 16 + l15 + 1 - dwi) & 127;
      alut[dwi][m] = ws * 128 + ((l4 ^ (ws & 7)) << 4);
    }

  bf16x8 breg[3][4][2];   // triple buffer, all-static indexing

  // ---- prologue: B(0)->buf0, B(1)->buf1, stage rows h0-1..h0+1 -> slots 0..2
  #pragma unroll
  for (int n = 0; n < 4; ++n)
    #pragma unroll
    for (int kk = 0; kk < 2; ++kk) {
      breg[0][n][kk] = *(const bf16x8*)(btb + bofs + n * 2048 + kk * 1024);
      breg[1][n][kk] = *(const bf16x8*)(btb + 32768 + bofs + n * 2048 + kk * 1024);
    }

  #pragma unroll
  for (int i = 0; i < 6; ++i) {
    int idx = tid + i * 512;            // 3072 16B-blocks (3 rows)
    int cb = idx & 7;
    int w  = (idx >> 3) & 127;
    int r  = idx >> 10;                 // 0..2 -> slot r
    int xr = (h0 + r + 127) & 127;      // row h0-1+r
    const float* src = x + (((size_t)(bb * NH + xr) * NW + w) * NC + cb * 8);
    float4 a0 = *(const float4*)(src);
    float4 a1 = *(const float4*)(src + 4);
    union { unsigned short u[8]; i32x4 v; } p;
    p.u[0] = f2b(a0.x); p.u[1] = f2b(a0.y); p.u[2] = f2b(a0.z); p.u[3] = f2b(a0.w);
    p.u[4] = f2b(a1.x); p.u[5] = f2b(a1.y); p.u[6] = f2b(a1.z); p.u[7] = f2b(a1.w);
    *(i32x4*)(lds + (r * SLOT + w * 128 + ((cb ^ (w & 7)) << 4))) = p.v;
  }

  float bv[4];
  #pragma unroll
  for (int n = 0; n < 4; ++n) bv[n] = bias[wn * 64 + n * 16 + l15];

  __syncthreads();

  const int scb0 = tid & 7,          sw0 = tid >> 3;            // w 0..63
  const int scb1 = (tid + 512) & 7,  sw1 = ((tid + 512) >> 3) & 127;  // w 64..127

  f32x4 acc[4][4];

  #pragma unroll 1
  for (int j = 0; j < 4; ++j) {
    #pragma unroll
    for (int m = 0; m < 4; ++m)
      #pragma unroll
      for (int n = 0; n < 4; ++n)
        acc[m][n] = (f32x4){0.f, 0.f, 0.f, 0.f};

    // issue next-row x loads (row h0+j+2 -> slot (j+3)&3, written at s==4)
    const bool dostage = (j < 3);
    float4 xv[4];
    if (dostage) {
      int xr2 = (h0 + j + 2) & 127;
      const float* xrow = x + (size_t)(bb * NH + xr2) * NW * NC;
      const float* s0 = xrow + sw0 * NC + scb0 * 8;
      const float* s1 = xrow + sw1 * NC + scb1 * 8;
      xv[0] = *(const float4*)(s0); xv[1] = *(const float4*)(s0 + 4);
      xv[2] = *(const float4*)(s1); xv[3] = *(const float4*)(s1 + 4);
    }
    const int wslotb = ((j + 3) & 3) * SLOT;

    #pragma unroll
    for (int s = 0; s < 9; ++s) {
      // 2-deep B prefetch: issue B((s+2)%9) into just-freed buffer (s+2)%3.
      // Uniform across steps (9 % 3 == 0): s=7 issues next step's B(0)->buf0,
      // s=8 issues next step's B(1)->buf1.
      {
        const char* bs = btb + (size_t)(((s + 2) % 9) * 32768) + bofs;
        #pragma unroll
        for (int n = 0; n < 4; ++n)
          #pragma unroll
          for (int kk = 0; kk < 2; ++kk)
            breg[(s + 2) % 3][n][kk] = *(const bf16x8*)(bs + n * 2048 + kk * 1024);
      }
      if (s == 4 && dostage) {  // write staged row (slot unused this step)
        #pragma unroll
        for (int hblk = 0; hblk < 2; ++hblk) {
          int cb = hblk ? scb1 : scb0;
          int w  = hblk ? sw1  : sw0;
          union { unsigned short u[8]; i32x4 v; } p;
          float4 a0 = xv[hblk * 2], a1 = xv[hblk * 2 + 1];
          p.u[0] = f2b(a0.x); p.u[1] = f2b(a0.y); p.u[2] = f2b(a0.z); p.u[3] = f2b(a0.w);
          p.u[4] = f2b(a1.x); p.u[5] = f2b(a1.y); p.u[6] = f2b(a1.z); p.u[7] = f2b(a1.w);
          *(i32x4*)(lds + (wslotb + w * 128 + ((cb ^ (w & 7)) << 4))) = p.v;
        }
      }
      const int dwi = s / 3;                                   // static
      const int slotb = ((j + 2 - (s % 3)) & 3) * SLOT;        // x-row slot
      #pragma unroll
      for (int kk = 0; kk < 2; ++kk) {
        bf16x8 af[4];
        #pragma unroll
        for (int m = 0; m < 4; ++m)
          af[m] = *(const bf16x8*)(lds + ((slotb + alut[dwi][m]) ^ (kk << 6)));
        #pragma unroll
        for (int m = 0; m < 4; ++m)
          #pragma unroll
          for (int n = 0; n < 4; ++n)
            acc[m][n] = __builtin_amdgcn_mfma_f32_16x16x32_bf16(
                af[m], breg[s % 3][n][kk], acc[m][n], 0, 0, 0);
      }
    }

    // stores for row h0+j (fire-and-forget)
    {
      size_t orow = ((size_t)(bb * NH + h0 + j) * NW) * NF;
      #pragma unroll
      for (int m = 0; m < 4; ++m)
        #pragma unroll
        for (int jj = 0; jj < 4; ++jj) {
          int w = wm * 64 + m * 16 + l4 * 4 + jj;
          float* op = out + orow + (size_t)w * NF + wn * 64;
          #pragma unroll
          for (int n = 0; n < 4; ++n)
            op[n * 16 + l15] = acc[m][n][jj] + bv[n];
        }
    }
    __syncthreads();   // step boundary: staged slot visible, old slot reusable
  }
}

extern "C" void kernel_launch(void* const* d_in, const int* in_sizes, int n_in,
                              void* d_out, int out_size, void* d_ws, size_t ws_size,
                              hipStream_t stream) {
  const float* x    = (const float*)d_in[0];
  const float* kern = (const float*)d_in[1];
  const float* bias = (const float*)d_in[2];
  float* out = (float*)d_out;
  unsigned short* bt = (unsigned short*)d_ws;   // 294912 bytes

  prep_bt<<<dim3(72), dim3(256), 0, stream>>>(kern, bt);
  conv_main<<<dim3(512), dim3(512), 0, stream>>>(x, bt, bias, out);
}

// Round 8
// 111.443 us; speedup vs baseline: 2.2010x; 2.2010x over previous
//
#include <hip/hip_runtime.h>
#include <stdint.h>
#include <stddef.h>

typedef __attribute__((ext_vector_type(8))) short bf16x8;
typedef __attribute__((ext_vector_type(4))) float f32x4;
typedef __attribute__((ext_vector_type(4))) int i32x4;

#define NH 128
#define NW 128
#define NC 64
#define NF 256
#define SLOT 16384                 // one x-row image: [w=128][cb=8 x 16B], XOR-swizzled
#define XOFF 294912                // byte offset of x images in ws (after 288 KB B table)
#define WS_NEED (XOFF + 2048 * SLOT)

__device__ __forceinline__ unsigned short f2b(float f) {
  union { float f; uint32_t u; } t; t.f = f;
  uint32_t u = t.u;
  return (unsigned short)((u + 0x7fffu + ((u >> 16) & 1u)) >> 16);
}

__device__ __forceinline__ void gload16(const void* g, void* l) {
  __builtin_amdgcn_global_load_lds(
      (const __attribute__((address_space(1))) unsigned int*)g,
      (__attribute__((address_space(3))) unsigned int*)l, 16, 0, 0);
}

// Combined prep:
//  blocks [0,72):   B table in per-wave fragment order (R5-verified):
//    u16 elem ((fi*9+s)*16 + cf*2 + kk)*512 + lane*8 + e
//      = kern[(s*64 + (kk*4+(lane>>4))*8 + e)*NF + fi*128 + cf*16 + (lane&15)]
//  blocks [72,...): x -> bf16 swizzled 16KB row-images at XOFF (DMA path only):
//    image (b*128+h), byte w*128 + ((cb^(w&7))<<4) = x[b,h,w,cb*8..+8]
__global__ void prep_all(const float* __restrict__ x, const float* __restrict__ kr,
                         unsigned short* __restrict__ ws) {
  int bid = (int)blockIdx.x;
  if (bid < 72) {
    int t = bid * 256 + threadIdx.x;   // [0, 18432)
    int lane = t & 63;
    int kk   = (t >> 6) & 1;
    int cf   = (t >> 7) & 7;
    int rest = t >> 10;          // fi*9 + s
    int s  = rest % 9;
    int fi = rest / 9;
    int l15 = lane & 15, l4 = lane >> 4;
    int col = fi * 128 + cf * 16 + l15;
    int k0  = s * 64 + (kk * 4 + l4) * 8;
    unsigned short* dst = ws + (size_t)t * 8;
    const float* src = kr + (size_t)k0 * NF + col;
    #pragma unroll
    for (int e = 0; e < 8; ++e) dst[e] = f2b(src[(size_t)e * NF]);
  } else {
    int idx = (bid - 72) * 256 + threadIdx.x;   // [0, 2097152) 16B tasks
    int q   = idx & 1023;
    int row = idx >> 10;                        // b*128+h
    int w = q >> 3, cb = q & 7;
    const float* src = x + ((size_t)row * NW + w) * NC + cb * 8;
    float4 a0 = *(const float4*)(src);
    float4 a1 = *(const float4*)(src + 4);
    union { unsigned short u[8]; i32x4 v; } p;
    p.u[0] = f2b(a0.x); p.u[1] = f2b(a0.y); p.u[2] = f2b(a0.z); p.u[3] = f2b(a0.w);
    p.u[4] = f2b(a1.x); p.u[5] = f2b(a1.y); p.u[6] = f2b(a1.z); p.u[7] = f2b(a1.w);
    *(i32x4*)((char*)ws + XOFF + (size_t)row * SLOT + w * 128 + ((cb ^ (w & 7)) << 4)) = p.v;
  }
}

// conv: block = one (b,h) x half-N. LDS = A only (48 KB), barrier-free loop.
// DMA_A: A rows staged via global_load_lds from pre-swizzled ws images.
// B: register TRIPLE buffer, prefetched 2 shifts ahead (needs VGPR headroom:
// launch_bounds(256,2) -> cap 256, 2 blocks/CU).
template<bool DMA_A>
__global__ __launch_bounds__(256, 2)
void conv_main(const float* __restrict__ x, const unsigned short* __restrict__ bt,
               const float* __restrict__ bias, float* __restrict__ out)
{
  __shared__ __align__(16) char lds[3 * SLOT];   // 48 KB; epilogue reuses

  const int tid  = threadIdx.x;
  const int lane = tid & 63;
  const int l15  = lane & 15;
  const int l4   = lane >> 4;
  const int wid  = tid >> 6;
  const int wm   = wid >> 1;    // 2: w-half
  const int wn   = wid & 1;     // 2: F-quarter

  // XCD-aware bijective swizzle: nwg=4096, 512 per XCD.
  int bid  = (int)blockIdx.x;
  int work = (bid & 7) * 512 + (bid >> 3);
  int mi = work >> 1;           // (b,h) flat
  int fi = work & 1;
  int bb = mi >> 7;
  int hh = mi & 127;
  int F0 = fi * 128;

  const char* bimg = (const char*)bt + (size_t)fi * 9 * 16384;
  const int boff = (wn * 4) * 2048 + lane * 16;

  // A-frag byte offsets within a slot: aoff[dwi][m], kk=1 = kk=0 XOR 64
  int aoff[3][4];
  #pragma unroll
  for (int dwi = 0; dwi < 3; ++dwi)
    #pragma unroll
    for (int m = 0; m < 4; ++m) {
      int wsrc = (wm * 64 + m * 16 + l15 + 1 - dwi) & 127;
      aoff[dwi][m] = wsrc * 128 + ((l4 ^ (wsrc & 7)) << 4);
    }

  bf16x8 breg[3][4][2];   // triple buffer, all-static indices

  // ---- prologue: B(0)->buf0, B(1)->buf1 ----
  #pragma unroll
  for (int n = 0; n < 4; ++n)
    #pragma unroll
    for (int kk = 0; kk < 2; ++kk) {
      breg[0][n][kk] = *(const bf16x8*)(bimg + boff + n * 2048 + kk * 1024);
      breg[1][n][kk] = *(const bf16x8*)(bimg + 16384 + boff + n * 2048 + kk * 1024);
    }

  // ---- stage A rows h-1,h,h+1 -> slots 0..2 ----
  if constexpr (DMA_A) {
    const char* xim = (const char*)bt + XOFF;
    #pragma unroll
    for (int r = 0; r < 3; ++r) {
      int xr = (hh + r + 127) & 127;
      const char* src = xim + ((size_t)(bb * NH + xr)) * SLOT;
      #pragma unroll
      for (int i = 0; i < 4; ++i) {
        int byte = tid * 16 + i * 4096;
        gload16(src + byte, lds + r * SLOT + byte);
      }
    }
  } else {
    #pragma unroll
    for (int i = 0; i < 12; ++i) {
      int idx = tid + i * 256;
      int cb = idx & 7;
      int w  = (idx >> 3) & 127;
      int r  = idx >> 10;
      int xr = (hh + r + 127) & 127;
      const float* src = x + (((size_t)(bb * NH + xr) * NW + w) * NC + cb * 8);
      float4 a0 = *(const float4*)(src);
      float4 a1 = *(const float4*)(src + 4);
      union { unsigned short u[8]; i32x4 v; } p;
      p.u[0] = f2b(a0.x); p.u[1] = f2b(a0.y); p.u[2] = f2b(a0.z); p.u[3] = f2b(a0.w);
      p.u[4] = f2b(a1.x); p.u[5] = f2b(a1.y); p.u[6] = f2b(a1.z); p.u[7] = f2b(a1.w);
      *(i32x4*)(lds + (r * SLOT + w * 128 + ((cb ^ (w & 7)) << 4))) = p.v;
    }
  }
  __syncthreads();    // drains DMA vmcnt + B0/B1; A read-only hereafter

  f32x4 acc[4][4];
  #pragma unroll
  for (int m = 0; m < 4; ++m)
    #pragma unroll
    for (int n = 0; n < 4; ++n)
      acc[m][n] = (f32x4){0.f, 0.f, 0.f, 0.f};

  #pragma unroll
  for (int s = 0; s < 9; ++s) {
    if (s < 7) {  // 2-deep prefetch: B(s+2) -> just-freed buffer (s+2)%3
      const char* bs = bimg + (size_t)(s + 2) * 16384 + boff;
      #pragma unroll
      for (int n = 0; n < 4; ++n)
        #pragma unroll
        for (int kk = 0; kk < 2; ++kk)
          breg[(s + 2) % 3][n][kk] = *(const bf16x8*)(bs + n * 2048 + kk * 1024);
    }
    const int dwi   = s / 3;                  // static
    const int slotb = (2 - (s % 3)) * SLOT;   // static
    #pragma unroll
    for (int kk = 0; kk < 2; ++kk) {
      bf16x8 af[4];
      #pragma unroll
      for (int m = 0; m < 4; ++m)
        af[m] = *(const bf16x8*)(lds + ((slotb + aoff[dwi][m]) ^ (kk << 6)));
      #pragma unroll
      for (int m = 0; m < 4; ++m)
        #pragma unroll
        for (int n = 0; n < 4; ++n)
          acc[m][n] = __builtin_amdgcn_mfma_f32_16x16x32_bf16(
              af[m], breg[s % 3][n][kk], acc[m][n], 0, 0, 0);
    }
  }

  // ---- epilogue: bias + FULL-LINE stores via LDS transpose (R5-verified) ----
  float bv[4];
  #pragma unroll
  for (int n = 0; n < 4; ++n) bv[n] = bias[F0 + wn * 64 + n * 16 + l15];

  __syncthreads();
  float* eb = (float*)lds;              // [64][132] padded f32 tile

  #pragma unroll
  for (int chunk = 0; chunk < 2; ++chunk) {
    if (wm == chunk) {
      #pragma unroll
      for (int m = 0; m < 4; ++m)
        #pragma unroll
        for (int jj = 0; jj < 4; ++jj) {
          int r = m * 16 + l4 * 4 + jj;
          #pragma unroll
          for (int n = 0; n < 4; ++n)
            eb[r * 132 + wn * 64 + n * 16 + l15] = acc[m][n][jj] + bv[n];
        }
    }
    __syncthreads();
    size_t obase = ((size_t)mi * 128 + chunk * 64) * NF + F0;
    #pragma unroll
    for (int i = 0; i < 8; ++i) {
      int r = i * 8 + wid * 2 + (lane >> 5);
      int c = (lane & 31) * 4;
      f32x4 v = *(const f32x4*)(eb + r * 132 + c);
      *(f32x4*)(out + obase + (size_t)r * NF + c) = v;
    }
    if (chunk == 0) __syncthreads();
  }
}

extern "C" void kernel_launch(void* const* d_in, const int* in_sizes, int n_in,
                              void* d_out, int out_size, void* d_ws, size_t ws_size,
                              hipStream_t stream) {
  const float* x    = (const float*)d_in[0];
  const float* kern = (const float*)d_in[1];
  const float* bias = (const float*)d_in[2];
  float* out = (float*)d_out;
  unsigned short* bt = (unsigned short*)d_ws;

  if (ws_size >= (size_t)WS_NEED) {
    prep_all<<<dim3(72 + 8192), dim3(256), 0, stream>>>(x, kern, bt);
    conv_main<true><<<dim3(4096), dim3(256), 0, stream>>>(x, bt, bias, out);
  } else {
    prep_all<<<dim3(72), dim3(256), 0, stream>>>(x, kern, bt);
    conv_main<false><<<dim3(4096), dim3(256), 0, stream>>>(x, bt, bias, out);
  }
}